// Round 7
// baseline (794.816 us; speedup 1.0000x reference)
//
#include <hip/hip_runtime.h>

// DesignerNetwork: B=1024 batch-independent graph-GRU network.
// Round 5 kernel, third submission (two consecutive broker timeouts, never
// executed): (a) weights pre-packed into d_ws by a prep kernel (padded,
// per-(gate,lane,wave) contiguous v2f slices -> rematerializable vector
// loads, no spill, pk_fma-friendly); (b) chunked successor batching (<=4
// per exchange, 2 barriers/chunk) with per-wave split finalize.

namespace {

typedef float v2f __attribute__((ext_vector_type(2)));

constexpr int Bc = 1024;   // batch
constexpr int Nn = 32;     // nodes
constexpr int SP = 60;     // S_PHI == S_RHO
constexpr int NA = 5;      // actions
constexpr int NR = 7;      // roles

// ---- d_ws float layout (packed weights) ----
// WHH: [dir2][gate3][lane64][wave4][16f]  = 24576 floats @ 0
// WIH: same                               = 24576 floats @ 24576
// WP : [dir2][lane64][wave4][20f]         = 10240 floats @ 49152
constexpr int WS_WIH = 24576;
constexpr int WS_WP  = 49152;
constexpr int WS_TOTAL = 59392;
constexpr int DSTRIDE_G = 12288;   // per-dir stride for WHH/WIH regions
constexpr int DSTRIDE_P = 5120;    // per-dir stride for WP region

// ---- LDS layout (float offsets) ----
constexpr int OFF_ST   = 0;                    // states [32][64]
constexpr int OFF_RP   = OFF_ST + Nn * 64;     // rho partials [2][4][64]
constexpr int OFF_PART = OFF_RP + 512;         // chunk partials [4][4][64][4]
constexpr int OFF_ZDZ  = OFF_PART + 4096;      // z/dz staged [32][20]
constexpr int OFF_PSI  = OFF_ZDZ + Nn * 20;    // psi raw [32][8]
constexpr int OFF_WU   = OFF_PSI + Nn * 8;     // Wu 7x120
constexpr int OFF_WA   = OFF_WU + 840;         // Wa 5x120
constexpr int OFF_WC   = OFF_WA + 600;         // Wc 120
constexpr int OFF_BA   = OFF_WC + 120;         // ba (pad 8)
constexpr int OFF_BU   = OFF_BA + 8;           // bu (pad 8)
constexpr int OFF_BC   = OFF_BU + 8;           // bc (pad 4)
constexpr int OFF_HAS  = OFF_BC + 4;           // has[32]
constexpr int OFF_AF   = OFF_HAS + 32;         // alpha_f [64]
constexpr int OFF_AB   = OFF_AF + 64;          // alpha_b [64]
constexpr int OFF_OS   = OFF_AB + 64;          // omega scratch [8]
constexpr int OFF_MASK = OFF_OS + 8;           // uints: succ[32] pred[32] flags[4]
constexpr int LDS_FLOATS = OFF_MASK + 68 + 8;  // 9376 floats = 37.5KB

__device__ __forceinline__ float sigm(float x) {
    return 1.0f / (1.0f + __expf(-x));
}

__device__ __forceinline__ float tanh_f(float x) {
    float e = __expf(fminf(2.0f * x, 80.0f));
    return (e - 1.0f) / (e + 1.0f);
}

// adj may arrive as int32 (0/1), packed uint8 bool, or float32. mode: 0/1/2.
__device__ __forceinline__ unsigned adj_nz(const unsigned* a, int mode, int r, int c) {
    const int idx = r * 32 + c;
    unsigned v = (mode == 1) ? ((a[idx >> 2] >> (8 * (idx & 3))) & 0xffu) : a[idx];
    return v != 0u ? 1u : 0u;
}

// 3-gate dot of this thread's packed weight slice W (gates at +0,+2048,+4096
// v2f) with 8-v2f x slice. Pads are zero on both sides.
__device__ __forceinline__ void matvec3(const v2f* __restrict__ W, const v2f* x,
                                        float& r0, float& r1, float& r2) {
    v2f a0 = {0.f, 0.f}, a1 = {0.f, 0.f}, a2 = {0.f, 0.f};
#pragma unroll
    for (int p = 0; p < 8; ++p) {
        const v2f xp = x[p];
        a0 = __builtin_elementwise_fma(W[p],        xp, a0);
        a1 = __builtin_elementwise_fma(W[2048 + p], xp, a1);
        a2 = __builtin_elementwise_fma(W[4096 + p], xp, a2);
    }
    r0 = a0.x + a0.y; r1 = a1.x + a1.y; r2 = a2.x + a2.y;
}

// ---- weight pre-pack kernel (runs before dn_kernel on the same stream) ----
__global__ void pack_kernel(const float* __restrict__ Whh_f, const float* __restrict__ Wih_f,
                            const float* __restrict__ Wf,
                            const float* __restrict__ Whh_b, const float* __restrict__ Wih_b,
                            const float* __restrict__ Wb, float* __restrict__ ws) {
    const int idx = blockIdx.x * 256 + threadIdx.x;
    if (idx < 2 * 24576) {
        const int which = idx / 24576;      // 0=WHH, 1=WIH
        int r = idx % 24576;
        const int j = r & 15; r >>= 4;
        const int w = r & 3;  r >>= 2;
        const int lane = r & 63; r >>= 6;
        const int g = r % 3;
        const int d = r / 3;
        const int k = 16 * w + j;
        const float* src = which ? (d ? Wih_b : Wih_f) : (d ? Whh_b : Whh_f);
        ws[idx] = (lane < 60 && k < 60) ? src[(g * 60 + lane) * 60 + k] : 0.f;
    } else if (idx < WS_TOTAL) {
        int r = idx - WS_WP;
        const int jj = r % 20; r /= 20;
        const int w = r & 3;  r >>= 2;
        const int lane = r & 63;
        const int d = r >> 6;
        const float* src = d ? Wb : Wf;
        const int pk = (w < 3) ? 20 * w : 60;
        ws[idx] = (lane < 60) ? src[lane * 80 + pk + jj] : 0.f;
    }
}

template <int FWD>
__device__ __forceinline__ void run_dir(float* lds, const float* __restrict__ ws,
        const float* __restrict__ bih, const float* __restrict__ bhh,
        const float* __restrict__ bp, int w, int lane, int ln, int& par) {
    float* st = lds + OFF_ST;
    const unsigned* succm = (const unsigned*)(lds + OFF_MASK);
    const unsigned* predm = succm + 32;
    const int d = FWD ? 0 : 1;

    // per-thread packed-weight slices (plain global pointers: rematerializable)
    const v2f* WH = (const v2f*)(ws + d * DSTRIDE_G + ((lane * 4 + w) << 4));
    const v2f* WX = (const v2f*)(ws + WS_WIH + d * DSTRIDE_G + ((lane * 4 + w) << 4));
    const v2f* WP = (const v2f*)(ws + WS_WP + d * DSTRIDE_P + (lane * 4 + w) * 20);

    const float b0s = bih[ln] + bhh[ln];
    const float b1s = bih[60 + ln] + bhh[60 + ln];
    const float b2i = bih[120 + ln];
    const float b2h = bhh[120 + ln];
    const float bpv = bp[ln];

    for (int s = 0; s < Nn; ++s) {
        const int t = FWD ? s : (Nn - 1 - s);

        // ---- finalize rho[t]: cooperative proj over [h(60); z(10); dz(10)] ----
        v2f pa = {0.f, 0.f};
        const v2f* xb = (w < 3) ? ((const v2f*)(st + t * 64) + 10 * w)
                                : ((const v2f*)(lds + OFF_ZDZ + t * 20));
#pragma unroll
        for (int p = 0; p < 10; ++p)
            pa = __builtin_elementwise_fma(WP[p], xb[p], pa);
        lds[OFF_RP + (par * 4 + w) * 64 + lane] = pa.x + pa.y;
        __syncthreads();
        float sum = lds[OFF_RP + (par * 4 + 0) * 64 + lane]
                  + lds[OFF_RP + (par * 4 + 1) * 64 + lane]
                  + lds[OFF_RP + (par * 4 + 2) * 64 + lane]
                  + lds[OFF_RP + (par * 4 + 3) * 64 + lane] + bpv;
        par ^= 1;
        const float rho = FWD ? tanh_f(sum) : sum;
        if (lane < SP) st[t * 64 + lane] = rho;   // replicated identical write
        // (own-wave LDS write->read below is in-order; no barrier needed)

        // ---- GRU pushes, gated by has[t]; successors batched 4 per round ----
        const float hb = lds[OFF_HAS + t];
        unsigned m = (hb != 0.f) ? (FWD ? succm[t] : predm[t]) : 0u;
        if (m) {
            float gi0, gi1, gi2;      // x-side slice of rho[t], hoisted per node
            matvec3(WX, (const v2f*)(st + t * 64) + 8 * w, gi0, gi1, gi2);
            while (m) {
                int i0 = __ffs(m) - 1; m &= m - 1u;
                int i1 = -1, i2 = -1, i3 = -1, cnt = 1;
                if (m) { i1 = __ffs(m) - 1; m &= m - 1u; ++cnt;
                    if (m) { i2 = __ffs(m) - 1; m &= m - 1u; ++cnt;
                        if (m) { i3 = __ffs(m) - 1; m &= m - 1u; ++cnt; } } }
                {
                    float g0, g1, g2;
                    matvec3(WH, (const v2f*)(st + i0 * 64) + 8 * w, g0, g1, g2);
                    float4 q = {gi0 + g0, gi1 + g1, gi2, g2};
                    *(float4*)(lds + OFF_PART + ((0 * 4 + w) * 64 + lane) * 4) = q;
                }
                if (cnt > 1) {
                    float g0, g1, g2;
                    matvec3(WH, (const v2f*)(st + i1 * 64) + 8 * w, g0, g1, g2);
                    float4 q = {gi0 + g0, gi1 + g1, gi2, g2};
                    *(float4*)(lds + OFF_PART + ((1 * 4 + w) * 64 + lane) * 4) = q;
                }
                if (cnt > 2) {
                    float g0, g1, g2;
                    matvec3(WH, (const v2f*)(st + i2 * 64) + 8 * w, g0, g1, g2);
                    float4 q = {gi0 + g0, gi1 + g1, gi2, g2};
                    *(float4*)(lds + OFF_PART + ((2 * 4 + w) * 64 + lane) * 4) = q;
                }
                if (cnt > 3) {
                    float g0, g1, g2;
                    matvec3(WH, (const v2f*)(st + i3 * 64) + 8 * w, g0, g1, g2);
                    float4 q = {gi0 + g0, gi1 + g1, gi2, g2};
                    *(float4*)(lds + OFF_PART + ((3 * 4 + w) * 64 + lane) * 4) = q;
                }
                __syncthreads();
                if (w < cnt) {        // wave w finalizes successor #w of chunk
                    const int it = (w == 0) ? i0 : (w == 1) ? i1 : (w == 2) ? i2 : i3;
                    const float4 q0 = *(const float4*)(lds + OFF_PART + ((w * 4 + 0) * 64 + lane) * 4);
                    const float4 q1 = *(const float4*)(lds + OFF_PART + ((w * 4 + 1) * 64 + lane) * 4);
                    const float4 q2 = *(const float4*)(lds + OFF_PART + ((w * 4 + 2) * 64 + lane) * 4);
                    const float4 q3 = *(const float4*)(lds + OFF_PART + ((w * 4 + 3) * 64 + lane) * 4);
                    const float a0  = q0.x + q1.x + q2.x + q3.x + b0s;
                    const float a1  = q0.y + q1.y + q2.y + q3.y + b1s;
                    const float a2i = q0.z + q1.z + q2.z + q3.z + b2i;
                    const float a2h = q0.w + q1.w + q2.w + q3.w + b2h;
                    const float r = sigm(a0);
                    const float u = sigm(a1);
                    const float n = tanh_f(fmaf(r, a2h, a2i));
                    const float hold = st[it * 64 + lane];   // pre-update h
                    const float hnew = fmaf(u, hold - n, n);
                    if (lane < SP) st[it * 64 + lane] = hnew;
                }
                __syncthreads();
            }
        }
    }

    // ---- alpha scan (single GRU chain; wave 0 finalizes) ----
    float* ah = lds + (FWD ? OFF_AF : OFF_AB);
    ah[lane] = 0.f;                               // replicated identical write
    const int acn = FWD ? 5 : 6;
    for (int s2 = 0; s2 < acn; ++s2) {
        const int i = FWD ? (Nn - 5 + s2) : (5 - s2);
        if (lds[OFF_HAS + i] == 0.f) continue;    // block-uniform skip
        float gi0, gi1, gi2, g0, g1, g2;
        matvec3(WX, (const v2f*)(st + i * 64) + 8 * w, gi0, gi1, gi2);
        matvec3(WH, (const v2f*)(ah) + 8 * w, g0, g1, g2);
        float4 q = {gi0 + g0, gi1 + g1, gi2, g2};
        *(float4*)(lds + OFF_PART + (w * 64 + lane) * 4) = q;
        __syncthreads();
        if (w == 0) {
            const float4 q0 = *(const float4*)(lds + OFF_PART + ((0 * 64) + lane) * 4);
            const float4 q1 = *(const float4*)(lds + OFF_PART + ((1 * 64) + lane) * 4);
            const float4 q2 = *(const float4*)(lds + OFF_PART + ((2 * 64) + lane) * 4);
            const float4 q3 = *(const float4*)(lds + OFF_PART + ((3 * 64) + lane) * 4);
            const float a0  = q0.x + q1.x + q2.x + q3.x + b0s;
            const float a1  = q0.y + q1.y + q2.y + q3.y + b1s;
            const float a2i = q0.z + q1.z + q2.z + q3.z + b2i;
            const float a2h = q0.w + q1.w + q2.w + q3.w + b2h;
            const float r = sigm(a0);
            const float u = sigm(a1);
            const float n = tanh_f(fmaf(r, a2h, a2i));
            const float hold = ah[lane];
            const float hnew = fmaf(u, hold - n, n);
            if (lane < SP) ah[lane] = hnew;
        }
        __syncthreads();
    }
}

__device__ void run_heads(float* lds, int b, int lane, float* __restrict__ out) {
    const float* aF = lds + OFF_AF;
    const float* aB = lds + OFF_AB;

    float o = 0.f;
    if (lane < NA) {
        o = lds[OFF_BA + lane];
        const float* wa = lds + OFF_WA + lane * 120;
#pragma unroll
        for (int k = 0; k < SP; ++k) o = fmaf(wa[k], aF[k], o);
#pragma unroll
        for (int k = 0; k < SP; ++k) o = fmaf(wa[60 + k], aB[k], o);
        lds[OFF_OS + lane] = o;
    } else if (lane == NA) {
        float v = lds[OFF_BC];
        const float* wc = lds + OFF_WC;
#pragma unroll
        for (int k = 0; k < SP; ++k) v = fmaf(wc[k], aF[k], v);
#pragma unroll
        for (int k = 0; k < SP; ++k) v = fmaf(wc[60 + k], aB[k], v);
        out[Bc * NA + Bc * NR * Nn + b] = v;
    }
    __builtin_amdgcn_wave_barrier();

    if (lane < NA) {
        const float* os = lds + OFF_OS;
        float mx = os[0];
#pragma unroll
        for (int j = 1; j < NA; ++j) mx = fmaxf(mx, os[j]);
        float sum = 0.f;
#pragma unroll
        for (int j = 0; j < NA; ++j) sum += __expf(os[j] - mx);
        out[b * NA + lane] = __expf(o - mx) / sum;
    }

    if (lane < Nn) {
        const int i = lane;
        const float mk = lds[OFF_HAS + i];
        float p[NR];
        float mx = -1e30f;
#pragma unroll
        for (int c = 0; c < NR; ++c) {
            const float v = (mk != 0.f)
                ? (lds[OFF_PSI + i * 8 + c] + lds[OFF_BU + c])
                : -60.0f;
            p[c] = v;
            mx = fmaxf(mx, v);
        }
        float sum = 0.f;
#pragma unroll
        for (int c = 0; c < NR; ++c) { p[c] = __expf(p[c] - mx); sum += p[c]; }
        const float inv = 1.0f / sum;
#pragma unroll
        for (int c = 0; c < NR; ++c)
            out[Bc * NA + b * (NR * Nn) + c * Nn + i] = p[c] * inv;
    }
}

__global__ __launch_bounds__(256, 3)
void dn_kernel(const float* __restrict__ has, const float* __restrict__ z,
               const float* __restrict__ dz, const unsigned* __restrict__ adjw,
               const float* __restrict__ bih_f, const float* __restrict__ bhh_f,
               const float* __restrict__ bih_b, const float* __restrict__ bhh_b,
               const float* __restrict__ bf, const float* __restrict__ bb,
               const float* __restrict__ Wa, const float* __restrict__ ba,
               const float* __restrict__ Wc, const float* __restrict__ bc,
               const float* __restrict__ Wu, const float* __restrict__ bu,
               const float* __restrict__ ws, float* __restrict__ out) {
    __shared__ float lds[LDS_FLOATS];
    const int tid = threadIdx.x;
    const int lane = tid & 63;
    const int w = tid >> 6;
    const int b = blockIdx.x;
    const int ln = (lane < SP) ? lane : (SP - 1);   // clamp for bias loads

    unsigned* succm = (unsigned*)(lds + OFF_MASK);
    unsigned* predm = succm + 32;
    unsigned* flags = predm + 32;

    if (tid < 4) flags[tid] = 0u;
    __syncthreads();

    // ---- adj dtype detection (first 256 words only) ----
    {
        unsigned ff = 0u, fb = 0u;
        for (int i = tid; i < 256; i += 256) {
            const unsigned v = adjw[i];
            ff |= (v == 0x3f800000u) ? 1u : 0u;
            fb |= (v > 1u && v != 0x3f800000u) ? 1u : 0u;
        }
        if (ff) atomicOr(&flags[0], 1u);
        if (fb) atomicOr(&flags[1], 1u);
    }

    // ---- stage head weights, has, z/dz; zero state array ----
    for (int i = tid; i < 840; i += 256) lds[OFF_WU + i] = Wu[i];
    for (int i = tid; i < 600; i += 256) lds[OFF_WA + i] = Wa[i];
    if (tid < 120) lds[OFF_WC + tid] = Wc[tid];
    if (tid < NR) lds[OFF_BU + tid] = bu[tid];
    if (tid < NA) lds[OFF_BA + tid] = ba[tid];
    if (tid == 0) lds[OFF_BC] = bc[0];
    if (tid < Nn) lds[OFF_HAS + tid] = has[b * 32 + tid];
    for (int i = tid; i < Nn * 20; i += 256) {
        const int t = i / 20, k = i - t * 20;
        lds[OFF_ZDZ + i] = (k < 10) ? z[(b * Nn + t) * 10 + k]
                                    : dz[(b * Nn + t) * 10 + (k - 10)];
    }
    for (int i = tid; i < Nn * 64; i += 256) lds[OFF_ST + i] = 0.f;
    __syncthreads();

    // ---- adjacency bitmasks ----
    const int mode = flags[0] ? 2 : (flags[1] ? 1 : 0);
    if (tid < 32) {
        unsigned sm = 0u;
        for (int c = 0; c < 32; ++c) sm |= adj_nz(adjw, mode, tid, c) << c;
        succm[tid] = sm;
    } else if (tid < 64) {
        const int c = tid - 32;
        unsigned pm = 0u;
        for (int r = 0; r < 32; ++r) pm |= adj_nz(adjw, mode, r, c) << r;
        predm[c] = pm;
    }
    __syncthreads();

    int par = 0;

    // ---- forward direction ----
    run_dir<1>(lds, ws, bih_f, bhh_f, bf, w, lane, ln, par);
    __syncthreads();

    // ---- psi pass 1 (fwd half) while rho_f still in ST ----
    if (tid < Nn * NR) {
        const int i = tid / NR, c = tid - i * NR;
        const float* wu = lds + OFF_WU + c * 120;
        const float* sf = lds + OFF_ST + i * 64;
        float acc = 0.f;
#pragma unroll
        for (int k = 0; k < SP; ++k) acc = fmaf(wu[k], sf[k], acc);
        lds[OFF_PSI + i * 8 + c] = acc;
    }
    __syncthreads();

    // ---- re-zero ST for backward direction ----
    for (int i = tid; i < Nn * 64; i += 256) lds[OFF_ST + i] = 0.f;
    __syncthreads();

    // ---- backward direction ----
    run_dir<0>(lds, ws, bih_b, bhh_b, bb, w, lane, ln, par);
    __syncthreads();

    // ---- psi pass 2 (bwd half) ----
    if (tid < Nn * NR) {
        const int i = tid / NR, c = tid - i * NR;
        const float* wu = lds + OFF_WU + c * 120 + 60;
        const float* sb = lds + OFF_ST + i * 64;
        float acc = 0.f;
#pragma unroll
        for (int k = 0; k < SP; ++k) acc = fmaf(wu[k], sb[k], acc);
        lds[OFF_PSI + i * 8 + c] += acc;
    }
    __syncthreads();

    if (w == 0) run_heads(lds, b, lane, out);
}

}  // namespace

extern "C" void kernel_launch(void* const* d_in, const int* in_sizes, int n_in,
                              void* d_out, int out_size, void* d_ws, size_t ws_size,
                              hipStream_t stream) {
    (void)in_sizes; (void)n_in; (void)out_size; (void)ws_size;
    const float* has     = (const float*)d_in[0];
    const float* z       = (const float*)d_in[1];
    const float* dz      = (const float*)d_in[2];
    const unsigned* adjw = (const unsigned*)d_in[3];
    const float* Wih_f   = (const float*)d_in[4];
    const float* Whh_f   = (const float*)d_in[5];
    const float* bih_f   = (const float*)d_in[6];
    const float* bhh_f   = (const float*)d_in[7];
    const float* Wih_b   = (const float*)d_in[8];
    const float* Whh_b   = (const float*)d_in[9];
    const float* bih_b   = (const float*)d_in[10];
    const float* bhh_b   = (const float*)d_in[11];
    const float* Wf      = (const float*)d_in[12];
    const float* bf      = (const float*)d_in[13];
    const float* Wb      = (const float*)d_in[14];
    const float* bb      = (const float*)d_in[15];
    const float* Wa      = (const float*)d_in[16];
    const float* ba      = (const float*)d_in[17];
    const float* Wc      = (const float*)d_in[18];
    const float* bc      = (const float*)d_in[19];
    const float* Wu      = (const float*)d_in[20];
    const float* bu      = (const float*)d_in[21];
    float* out = (float*)d_out;
    float* ws  = (float*)d_ws;   // needs WS_TOTAL*4 = 237.6KB of scratch

    pack_kernel<<<(WS_TOTAL + 255) / 256, 256, 0, stream>>>(
        Whh_f, Wih_f, Wf, Whh_b, Wih_b, Wb, ws);

    dn_kernel<<<Bc, 256, 0, stream>>>(
        has, z, dz, adjw,
        bih_f, bhh_f, bih_b, bhh_b, bf, bb,
        Wa, ba, Wc, bc, Wu, bu, ws, out);
}

// Round 8
// 367.747 us; speedup vs baseline: 2.1613x; 2.1613x over previous
//
#include <hip/hip_runtime.h>

// DesignerNetwork: B=1024 batch-independent graph-GRU network.
// Round 8: round-7 structure (packed d_ws, chunked successor batching,
// split finalize) + weight slices PINNED in VGPRs: loaded once per
// direction and multiplied by an asm-opaque 1.0f so the compiler can
// neither rematerialize (round-7 failure: per-iteration global re-loads,
// VALUBusy 15%) nor const-fold. __launch_bounds__(256,2) gives a 256-VGPR
// budget so the ~170 live registers never spill (round-4 failure).

namespace {

typedef float v2f __attribute__((ext_vector_type(2)));

constexpr int Bc = 1024;   // batch
constexpr int Nn = 32;     // nodes
constexpr int SP = 60;     // S_PHI == S_RHO
constexpr int NA = 5;      // actions
constexpr int NR = 7;      // roles

// ---- d_ws float layout (packed weights) ----
// WHH: [dir2][gate3][lane64][wave4][16f]  = 24576 floats @ 0
// WIH: same                               = 24576 floats @ 24576
// WP : [dir2][lane64][wave4][20f]         = 10240 floats @ 49152
constexpr int WS_WIH = 24576;
constexpr int WS_WP  = 49152;
constexpr int WS_TOTAL = 59392;
constexpr int DSTRIDE_G = 12288;   // per-dir stride for WHH/WIH regions
constexpr int DSTRIDE_P = 5120;    // per-dir stride for WP region

// ---- LDS layout (float offsets) ----
constexpr int OFF_ST   = 0;                    // states [32][64]
constexpr int OFF_RP   = OFF_ST + Nn * 64;     // rho partials [2][4][64]
constexpr int OFF_PART = OFF_RP + 512;         // chunk partials [4][4][64][4]
constexpr int OFF_ZDZ  = OFF_PART + 4096;      // z/dz staged [32][20]
constexpr int OFF_PSI  = OFF_ZDZ + Nn * 20;    // psi raw [32][8]
constexpr int OFF_WU   = OFF_PSI + Nn * 8;     // Wu 7x120
constexpr int OFF_WA   = OFF_WU + 840;         // Wa 5x120
constexpr int OFF_WC   = OFF_WA + 600;         // Wc 120
constexpr int OFF_BA   = OFF_WC + 120;         // ba (pad 8)
constexpr int OFF_BU   = OFF_BA + 8;           // bu (pad 8)
constexpr int OFF_BC   = OFF_BU + 8;           // bc (pad 4)
constexpr int OFF_HAS  = OFF_BC + 4;           // has[32]
constexpr int OFF_AF   = OFF_HAS + 32;         // alpha_f [64]
constexpr int OFF_AB   = OFF_AF + 64;          // alpha_b [64]
constexpr int OFF_OS   = OFF_AB + 64;          // omega scratch [8]
constexpr int OFF_MASK = OFF_OS + 8;           // uints: succ[32] pred[32] flags[4]
constexpr int LDS_FLOATS = OFF_MASK + 68 + 8;  // 9376 floats = 37.5KB

__device__ __forceinline__ float sigm(float x) {
    return 1.0f / (1.0f + __expf(-x));
}

__device__ __forceinline__ float tanh_f(float x) {
    float e = __expf(fminf(2.0f * x, 80.0f));
    return (e - 1.0f) / (e + 1.0f);
}

// adj may arrive as int32 (0/1), packed uint8 bool, or float32. mode: 0/1/2.
__device__ __forceinline__ unsigned adj_nz(const unsigned* a, int mode, int r, int c) {
    const int idx = r * 32 + c;
    unsigned v = (mode == 1) ? ((a[idx >> 2] >> (8 * (idx & 3))) & 0xffu) : a[idx];
    return v != 0u ? 1u : 0u;
}

// 3-gate dot of the register-resident weight slice with 8-v2f x slice.
__device__ __forceinline__ void matvec3(const v2f (&W)[3][8], const v2f* x,
                                        float& r0, float& r1, float& r2) {
    v2f a0 = {0.f, 0.f}, a1 = {0.f, 0.f}, a2 = {0.f, 0.f};
#pragma unroll
    for (int p = 0; p < 8; ++p) {
        const v2f xp = x[p];
        a0 = __builtin_elementwise_fma(W[0][p], xp, a0);
        a1 = __builtin_elementwise_fma(W[1][p], xp, a1);
        a2 = __builtin_elementwise_fma(W[2][p], xp, a2);
    }
    r0 = a0.x + a0.y; r1 = a1.x + a1.y; r2 = a2.x + a2.y;
}

// Load this thread's weight slices into registers, pinned via opaque *1.0f
// (product depends on a register -> not rematerializable, not foldable).
__device__ __forceinline__ void load_w(const float* __restrict__ ws, int d,
        int w, int lane, v2f onev,
        v2f (&wh)[3][8], v2f (&wx)[3][8], v2f (&wp)[10]) {
    const v2f* WH = (const v2f*)(ws + d * DSTRIDE_G + ((lane * 4 + w) << 4));
    const v2f* WX = (const v2f*)(ws + WS_WIH + d * DSTRIDE_G + ((lane * 4 + w) << 4));
    const v2f* WPp = (const v2f*)(ws + WS_WP + d * DSTRIDE_P + (lane * 4 + w) * 20);
#pragma unroll
    for (int g = 0; g < 3; ++g)
#pragma unroll
        for (int p = 0; p < 8; ++p) {
            wh[g][p] = WH[g * 2048 + p] * onev;
            wx[g][p] = WX[g * 2048 + p] * onev;
        }
#pragma unroll
    for (int p = 0; p < 10; ++p) wp[p] = WPp[p] * onev;
}

// ---- weight pre-pack kernel (runs before dn_kernel on the same stream) ----
__global__ void pack_kernel(const float* __restrict__ Whh_f, const float* __restrict__ Wih_f,
                            const float* __restrict__ Wf,
                            const float* __restrict__ Whh_b, const float* __restrict__ Wih_b,
                            const float* __restrict__ Wb, float* __restrict__ ws) {
    const int idx = blockIdx.x * 256 + threadIdx.x;
    if (idx < 2 * 24576) {
        const int which = idx / 24576;      // 0=WHH, 1=WIH
        int r = idx % 24576;
        const int j = r & 15; r >>= 4;
        const int w = r & 3;  r >>= 2;
        const int lane = r & 63; r >>= 6;
        const int g = r % 3;
        const int d = r / 3;
        const int k = 16 * w + j;
        const float* src = which ? (d ? Wih_b : Wih_f) : (d ? Whh_b : Whh_f);
        ws[idx] = (lane < 60 && k < 60) ? src[(g * 60 + lane) * 60 + k] : 0.f;
    } else if (idx < WS_TOTAL) {
        int r = idx - WS_WP;
        const int jj = r % 20; r /= 20;
        const int w = r & 3;  r >>= 2;
        const int lane = r & 63;
        const int d = r >> 6;
        const float* src = d ? Wb : Wf;
        const int pk = (w < 3) ? 20 * w : 60;
        ws[idx] = (lane < 60) ? src[lane * 80 + pk + jj] : 0.f;
    }
}

template <int FWD>
__device__ __forceinline__ void run_dir(float* lds,
        const v2f (&wh)[3][8], const v2f (&wx)[3][8], const v2f (&wp)[10],
        const float* __restrict__ bih, const float* __restrict__ bhh,
        const float* __restrict__ bp, int w, int lane, int ln, int& par) {
    float* st = lds + OFF_ST;
    const unsigned* succm = (const unsigned*)(lds + OFF_MASK);
    const unsigned* predm = succm + 32;

    const float b0s = bih[ln] + bhh[ln];
    const float b1s = bih[60 + ln] + bhh[60 + ln];
    const float b2i = bih[120 + ln];
    const float b2h = bhh[120 + ln];
    const float bpv = bp[ln];

    for (int s = 0; s < Nn; ++s) {
        const int t = FWD ? s : (Nn - 1 - s);

        // ---- finalize rho[t]: cooperative proj over [h(60); z(10); dz(10)] ----
        v2f pa = {0.f, 0.f};
        const v2f* xb = (w < 3) ? ((const v2f*)(st + t * 64) + 10 * w)
                                : ((const v2f*)(lds + OFF_ZDZ + t * 20));
#pragma unroll
        for (int p = 0; p < 10; ++p)
            pa = __builtin_elementwise_fma(wp[p], xb[p], pa);
        lds[OFF_RP + (par * 4 + w) * 64 + lane] = pa.x + pa.y;
        __syncthreads();
        float sum = lds[OFF_RP + (par * 4 + 0) * 64 + lane]
                  + lds[OFF_RP + (par * 4 + 1) * 64 + lane]
                  + lds[OFF_RP + (par * 4 + 2) * 64 + lane]
                  + lds[OFF_RP + (par * 4 + 3) * 64 + lane] + bpv;
        par ^= 1;
        const float rho = FWD ? tanh_f(sum) : sum;
        if (lane < SP) st[t * 64 + lane] = rho;   // replicated identical write
        // (own-wave LDS write->read below is in-order; no barrier needed)

        // ---- GRU pushes, gated by has[t]; successors batched 4 per round ----
        const float hb = lds[OFF_HAS + t];
        unsigned m = (hb != 0.f) ? (FWD ? succm[t] : predm[t]) : 0u;
        if (m) {
            float gi0, gi1, gi2;      // x-side slice of rho[t], hoisted per node
            matvec3(wx, (const v2f*)(st + t * 64) + 8 * w, gi0, gi1, gi2);
            while (m) {
                int i0 = __ffs(m) - 1; m &= m - 1u;
                int i1 = -1, i2 = -1, i3 = -1, cnt = 1;
                if (m) { i1 = __ffs(m) - 1; m &= m - 1u; ++cnt;
                    if (m) { i2 = __ffs(m) - 1; m &= m - 1u; ++cnt;
                        if (m) { i3 = __ffs(m) - 1; m &= m - 1u; ++cnt; } } }
                {
                    float g0, g1, g2;
                    matvec3(wh, (const v2f*)(st + i0 * 64) + 8 * w, g0, g1, g2);
                    float4 q = {gi0 + g0, gi1 + g1, gi2, g2};
                    *(float4*)(lds + OFF_PART + ((0 * 4 + w) * 64 + lane) * 4) = q;
                }
                if (cnt > 1) {
                    float g0, g1, g2;
                    matvec3(wh, (const v2f*)(st + i1 * 64) + 8 * w, g0, g1, g2);
                    float4 q = {gi0 + g0, gi1 + g1, gi2, g2};
                    *(float4*)(lds + OFF_PART + ((1 * 4 + w) * 64 + lane) * 4) = q;
                }
                if (cnt > 2) {
                    float g0, g1, g2;
                    matvec3(wh, (const v2f*)(st + i2 * 64) + 8 * w, g0, g1, g2);
                    float4 q = {gi0 + g0, gi1 + g1, gi2, g2};
                    *(float4*)(lds + OFF_PART + ((2 * 4 + w) * 64 + lane) * 4) = q;
                }
                if (cnt > 3) {
                    float g0, g1, g2;
                    matvec3(wh, (const v2f*)(st + i3 * 64) + 8 * w, g0, g1, g2);
                    float4 q = {gi0 + g0, gi1 + g1, gi2, g2};
                    *(float4*)(lds + OFF_PART + ((3 * 4 + w) * 64 + lane) * 4) = q;
                }
                __syncthreads();
                if (w < cnt) {        // wave w finalizes successor #w of chunk
                    const int it = (w == 0) ? i0 : (w == 1) ? i1 : (w == 2) ? i2 : i3;
                    const float4 q0 = *(const float4*)(lds + OFF_PART + ((w * 4 + 0) * 64 + lane) * 4);
                    const float4 q1 = *(const float4*)(lds + OFF_PART + ((w * 4 + 1) * 64 + lane) * 4);
                    const float4 q2 = *(const float4*)(lds + OFF_PART + ((w * 4 + 2) * 64 + lane) * 4);
                    const float4 q3 = *(const float4*)(lds + OFF_PART + ((w * 4 + 3) * 64 + lane) * 4);
                    const float a0  = q0.x + q1.x + q2.x + q3.x + b0s;
                    const float a1  = q0.y + q1.y + q2.y + q3.y + b1s;
                    const float a2i = q0.z + q1.z + q2.z + q3.z + b2i;
                    const float a2h = q0.w + q1.w + q2.w + q3.w + b2h;
                    const float r = sigm(a0);
                    const float u = sigm(a1);
                    const float n = tanh_f(fmaf(r, a2h, a2i));
                    const float hold = st[it * 64 + lane];   // pre-update h
                    const float hnew = fmaf(u, hold - n, n);
                    if (lane < SP) st[it * 64 + lane] = hnew;
                }
                __syncthreads();
            }
        }
    }

    // ---- alpha scan (single GRU chain; wave 0 finalizes) ----
    float* ah = lds + (FWD ? OFF_AF : OFF_AB);
    ah[lane] = 0.f;                               // replicated identical write
    const int acn = FWD ? 5 : 6;
    for (int s2 = 0; s2 < acn; ++s2) {
        const int i = FWD ? (Nn - 5 + s2) : (5 - s2);
        if (lds[OFF_HAS + i] == 0.f) continue;    // block-uniform skip
        float gi0, gi1, gi2, g0, g1, g2;
        matvec3(wx, (const v2f*)(st + i * 64) + 8 * w, gi0, gi1, gi2);
        matvec3(wh, (const v2f*)(ah) + 8 * w, g0, g1, g2);
        float4 q = {gi0 + g0, gi1 + g1, gi2, g2};
        *(float4*)(lds + OFF_PART + (w * 64 + lane) * 4) = q;
        __syncthreads();
        if (w == 0) {
            const float4 q0 = *(const float4*)(lds + OFF_PART + ((0 * 64) + lane) * 4);
            const float4 q1 = *(const float4*)(lds + OFF_PART + ((1 * 64) + lane) * 4);
            const float4 q2 = *(const float4*)(lds + OFF_PART + ((2 * 64) + lane) * 4);
            const float4 q3 = *(const float4*)(lds + OFF_PART + ((3 * 64) + lane) * 4);
            const float a0  = q0.x + q1.x + q2.x + q3.x + b0s;
            const float a1  = q0.y + q1.y + q2.y + q3.y + b1s;
            const float a2i = q0.z + q1.z + q2.z + q3.z + b2i;
            const float a2h = q0.w + q1.w + q2.w + q3.w + b2h;
            const float r = sigm(a0);
            const float u = sigm(a1);
            const float n = tanh_f(fmaf(r, a2h, a2i));
            const float hold = ah[lane];
            const float hnew = fmaf(u, hold - n, n);
            if (lane < SP) ah[lane] = hnew;
        }
        __syncthreads();
    }
}

__device__ void run_heads(float* lds, int b, int lane, float* __restrict__ out) {
    const float* aF = lds + OFF_AF;
    const float* aB = lds + OFF_AB;

    float o = 0.f;
    if (lane < NA) {
        o = lds[OFF_BA + lane];
        const float* wa = lds + OFF_WA + lane * 120;
#pragma unroll
        for (int k = 0; k < SP; ++k) o = fmaf(wa[k], aF[k], o);
#pragma unroll
        for (int k = 0; k < SP; ++k) o = fmaf(wa[60 + k], aB[k], o);
        lds[OFF_OS + lane] = o;
    } else if (lane == NA) {
        float v = lds[OFF_BC];
        const float* wc = lds + OFF_WC;
#pragma unroll
        for (int k = 0; k < SP; ++k) v = fmaf(wc[k], aF[k], v);
#pragma unroll
        for (int k = 0; k < SP; ++k) v = fmaf(wc[60 + k], aB[k], v);
        out[Bc * NA + Bc * NR * Nn + b] = v;
    }
    __builtin_amdgcn_wave_barrier();

    if (lane < NA) {
        const float* os = lds + OFF_OS;
        float mx = os[0];
#pragma unroll
        for (int j = 1; j < NA; ++j) mx = fmaxf(mx, os[j]);
        float sum = 0.f;
#pragma unroll
        for (int j = 0; j < NA; ++j) sum += __expf(os[j] - mx);
        out[b * NA + lane] = __expf(o - mx) / sum;
    }

    if (lane < Nn) {
        const int i = lane;
        const float mk = lds[OFF_HAS + i];
        float p[NR];
        float mx = -1e30f;
#pragma unroll
        for (int c = 0; c < NR; ++c) {
            const float v = (mk != 0.f)
                ? (lds[OFF_PSI + i * 8 + c] + lds[OFF_BU + c])
                : -60.0f;
            p[c] = v;
            mx = fmaxf(mx, v);
        }
        float sum = 0.f;
#pragma unroll
        for (int c = 0; c < NR; ++c) { p[c] = __expf(p[c] - mx); sum += p[c]; }
        const float inv = 1.0f / sum;
#pragma unroll
        for (int c = 0; c < NR; ++c)
            out[Bc * NA + b * (NR * Nn) + c * Nn + i] = p[c] * inv;
    }
}

__global__ __launch_bounds__(256, 2)
void dn_kernel(const float* __restrict__ has, const float* __restrict__ z,
               const float* __restrict__ dz, const unsigned* __restrict__ adjw,
               const float* __restrict__ bih_f, const float* __restrict__ bhh_f,
               const float* __restrict__ bih_b, const float* __restrict__ bhh_b,
               const float* __restrict__ bf, const float* __restrict__ bb,
               const float* __restrict__ Wa, const float* __restrict__ ba,
               const float* __restrict__ Wc, const float* __restrict__ bc,
               const float* __restrict__ Wu, const float* __restrict__ bu,
               const float* __restrict__ ws, float* __restrict__ out) {
    __shared__ float lds[LDS_FLOATS];
    const int tid = threadIdx.x;
    const int lane = tid & 63;
    const int w = tid >> 6;
    const int b = blockIdx.x;
    const int ln = (lane < SP) ? lane : (SP - 1);   // clamp for bias loads

    unsigned* succm = (unsigned*)(lds + OFF_MASK);
    unsigned* predm = succm + 32;
    unsigned* flags = predm + 32;

    if (tid < 4) flags[tid] = 0u;
    __syncthreads();

    // ---- adj dtype detection (first 256 words only) ----
    {
        unsigned ff = 0u, fb = 0u;
        for (int i = tid; i < 256; i += 256) {
            const unsigned v = adjw[i];
            ff |= (v == 0x3f800000u) ? 1u : 0u;
            fb |= (v > 1u && v != 0x3f800000u) ? 1u : 0u;
        }
        if (ff) atomicOr(&flags[0], 1u);
        if (fb) atomicOr(&flags[1], 1u);
    }

    // ---- stage head weights, has, z/dz; zero state array ----
    for (int i = tid; i < 840; i += 256) lds[OFF_WU + i] = Wu[i];
    for (int i = tid; i < 600; i += 256) lds[OFF_WA + i] = Wa[i];
    if (tid < 120) lds[OFF_WC + tid] = Wc[tid];
    if (tid < NR) lds[OFF_BU + tid] = bu[tid];
    if (tid < NA) lds[OFF_BA + tid] = ba[tid];
    if (tid == 0) lds[OFF_BC] = bc[0];
    if (tid < Nn) lds[OFF_HAS + tid] = has[b * 32 + tid];
    for (int i = tid; i < Nn * 20; i += 256) {
        const int t = i / 20, k = i - t * 20;
        lds[OFF_ZDZ + i] = (k < 10) ? z[(b * Nn + t) * 10 + k]
                                    : dz[(b * Nn + t) * 10 + (k - 10)];
    }
    for (int i = tid; i < Nn * 64; i += 256) lds[OFF_ST + i] = 0.f;
    __syncthreads();

    // ---- adjacency bitmasks ----
    const int mode = flags[0] ? 2 : (flags[1] ? 1 : 0);
    if (tid < 32) {
        unsigned sm = 0u;
        for (int c = 0; c < 32; ++c) sm |= adj_nz(adjw, mode, tid, c) << c;
        succm[tid] = sm;
    } else if (tid < 64) {
        const int c = tid - 32;
        unsigned pm = 0u;
        for (int r = 0; r < 32; ++r) pm |= adj_nz(adjw, mode, r, c) << r;
        predm[c] = pm;
    }
    __syncthreads();

    // ---- opaque 1.0f: pins weight registers against rematerialization ----
    float one = 1.0f;
    asm volatile("" : "+v"(one));
    const v2f onev = {one, one};

    int par = 0;
    v2f wh[3][8], wx[3][8], wp[10];

    // ---- forward direction ----
    load_w(ws, 0, w, lane, onev, wh, wx, wp);
    run_dir<1>(lds, wh, wx, wp, bih_f, bhh_f, bf, w, lane, ln, par);
    __syncthreads();

    // ---- psi pass 1 (fwd half) while rho_f still in ST ----
    if (tid < Nn * NR) {
        const int i = tid / NR, c = tid - i * NR;
        const float* wu = lds + OFF_WU + c * 120;
        const float* sf = lds + OFF_ST + i * 64;
        float acc = 0.f;
#pragma unroll
        for (int k = 0; k < SP; ++k) acc = fmaf(wu[k], sf[k], acc);
        lds[OFF_PSI + i * 8 + c] = acc;
    }
    __syncthreads();

    // ---- re-zero ST for backward direction ----
    for (int i = tid; i < Nn * 64; i += 256) lds[OFF_ST + i] = 0.f;
    __syncthreads();

    // ---- backward direction ----
    load_w(ws, 1, w, lane, onev, wh, wx, wp);
    run_dir<0>(lds, wh, wx, wp, bih_b, bhh_b, bb, w, lane, ln, par);
    __syncthreads();

    // ---- psi pass 2 (bwd half) ----
    if (tid < Nn * NR) {
        const int i = tid / NR, c = tid - i * NR;
        const float* wu = lds + OFF_WU + c * 120 + 60;
        const float* sb = lds + OFF_ST + i * 64;
        float acc = 0.f;
#pragma unroll
        for (int k = 0; k < SP; ++k) acc = fmaf(wu[k], sb[k], acc);
        lds[OFF_PSI + i * 8 + c] += acc;
    }
    __syncthreads();

    if (w == 0) run_heads(lds, b, lane, out);
}

}  // namespace

extern "C" void kernel_launch(void* const* d_in, const int* in_sizes, int n_in,
                              void* d_out, int out_size, void* d_ws, size_t ws_size,
                              hipStream_t stream) {
    (void)in_sizes; (void)n_in; (void)out_size; (void)ws_size;
    const float* has     = (const float*)d_in[0];
    const float* z       = (const float*)d_in[1];
    const float* dz      = (const float*)d_in[2];
    const unsigned* adjw = (const unsigned*)d_in[3];
    const float* Wih_f   = (const float*)d_in[4];
    const float* Whh_f   = (const float*)d_in[5];
    const float* bih_f   = (const float*)d_in[6];
    const float* bhh_f   = (const float*)d_in[7];
    const float* Wih_b   = (const float*)d_in[8];
    const float* Whh_b   = (const float*)d_in[9];
    const float* bih_b   = (const float*)d_in[10];
    const float* bhh_b   = (const float*)d_in[11];
    const float* Wf      = (const float*)d_in[12];
    const float* bf      = (const float*)d_in[13];
    const float* Wb      = (const float*)d_in[14];
    const float* bb      = (const float*)d_in[15];
    const float* Wa      = (const float*)d_in[16];
    const float* ba      = (const float*)d_in[17];
    const float* Wc      = (const float*)d_in[18];
    const float* bc      = (const float*)d_in[19];
    const float* Wu      = (const float*)d_in[20];
    const float* bu      = (const float*)d_in[21];
    float* out = (float*)d_out;
    float* ws  = (float*)d_ws;   // needs WS_TOTAL*4 = 237.6KB of scratch

    pack_kernel<<<(WS_TOTAL + 255) / 256, 256, 0, stream>>>(
        Whh_f, Wih_f, Wf, Whh_b, Wih_b, Wb, ws);

    dn_kernel<<<Bc, 256, 0, stream>>>(
        has, z, dz, adjw,
        bih_f, bhh_f, bih_b, bhh_b, bf, bb,
        Wa, ba, Wc, bc, Wu, bu, ws, out);
}